// Round 7
// baseline (48.757 us; speedup 1.0000x reference)
//
#include <hip/hip_runtime.h>
#include <math.h>

#define BB    16
#define LL    4096
#define TMAX  512
#define DIN   512
#define DHID  256
#define DOUT  3
#define NROW  (BB * TMAX)   // 8192
#define RPB   16            // rows per fused block

typedef __attribute__((ext_vector_type(8))) short bf16x8;   // 8 bf16 = 4 VGPR
typedef __attribute__((ext_vector_type(4))) float f32x4;

static __device__ __forceinline__ ushort f2bf(float x) {
    uint u = __builtin_bit_cast(uint, x);
    u = (u + 0x7FFFu + ((u >> 16) & 1u)) >> 16;
    return (ushort)u;
}

// ---------------------------------------------------------------------------
// ws layout (bytes):
//   [0    .. 32K )  starts (int[8192])
//   [32K  .. 64K )  lens   (int[8192])
//   [64K  .. 320K)  W1t bf16 [DHID][DIN] (ushort)
// ---------------------------------------------------------------------------

// ---------------------------------------------------------------------------
// Prep: blocks 0..15 = per-batch duration scan; blocks 16..47 = W1 transpose
// to bf16 [256][512] (64x64 tiles).
// ---------------------------------------------------------------------------
__global__ __launch_bounds__(512) void prep_kernel(
    const int* __restrict__ ds, const int* __restrict__ lmax,
    const float* __restrict__ W1, int* __restrict__ starts,
    int* __restrict__ lens, ushort* __restrict__ W1t) {
    __shared__ int   sbuf[TMAX];
    __shared__ float t[64][65];
    const int bid = blockIdx.x;
    const int tid = threadIdx.x;

    if (bid < BB) {                       // ---- scan ----
        const int b = bid;
        const float mult = (float)LL / (float)lmax[0];
        const int dsv = ds[b * TMAX + tid];
        int d = (int)floorf((float)dsv * mult);
        d = max(d, 1);
        const int deff = (dsv > 0) ? d : 0;
        sbuf[tid] = deff;
        __syncthreads();
        for (int off = 1; off < TMAX; off <<= 1) {
            int x = (tid >= off) ? sbuf[tid - off] : 0;
            __syncthreads();
            sbuf[tid] += x;
            __syncthreads();
        }
        starts[b * TMAX + tid] = sbuf[tid] - deff;
        lens[b * TMAX + tid]   = deff;
    } else {                              // ---- W1 transpose ----
        const int tb = bid - BB;          // 0..31: 8 k-tiles x 4 n-tiles
        const int k0 = (tb >> 2) * 64;
        const int n0 = (tb & 3) * 64;
        const int r  = tid >> 3;          // 0..63
        const int c8 = (tid & 7) * 8;     // 0..56
        #pragma unroll
        for (int i = 0; i < 2; ++i) {
            const float4 v =
                *(const float4*)&W1[(size_t)(k0 + r) * DHID + n0 + c8 + i * 4];
            t[r][c8 + i * 4 + 0] = v.x;
            t[r][c8 + i * 4 + 1] = v.y;
            t[r][c8 + i * 4 + 2] = v.z;
            t[r][c8 + i * 4 + 3] = v.w;
        }
        __syncthreads();
        #pragma unroll
        for (int i = 0; i < 2; ++i) {
            ushort4 u;
            u.x = f2bf(t[c8 + i * 4 + 0][r]);
            u.y = f2bf(t[c8 + i * 4 + 1][r]);
            u.z = f2bf(t[c8 + i * 4 + 2][r]);
            u.w = f2bf(t[c8 + i * 4 + 3][r]);
            *(ushort4*)&W1t[(size_t)(n0 + r) * DIN + k0 + c8 + i * 4] = u;
        }
    }
}

// ---------------------------------------------------------------------------
// Fused: segment-mean (16 rows -> swizzled LDS bf16 A-tile) + MFMA GEMM
// (16x256, K=512, B = W1t direct from L2) + fused layer-2 -> d_out.
// Phase 1: frame-index OUTER, row INNER (unrolled 16x) -- up to 16
//          independent loads in flight per thread (restores MLP at low
//          occupancy). All row state in statically-indexed registers.
//          Thread owns cols tid*2, tid*2+1; LDS write byte
//          (tid*4) ^ ((row&7)<<4)  (same involution as GEMM read).
// Phase 2: wave w owns cols w*64..w*64+63 (4 x 16x16x32 MFMA frags).
//   A-frag: lane holds A[row=l&15][k=8*(l>>4)+j] via swizzled 16B LDS read
//   B-frag: lane holds W1t[col][k] 16B global load (L2-resident)
//   C/D:    col = l&15, row = (l>>4)*4 + reg
// Grid = 512 blocks, XCD-chunked bijection (512 = 8 x 64).
// ---------------------------------------------------------------------------
__global__ __launch_bounds__(256, 2) void fused_kernel(
    const float* __restrict__ hs, const int* __restrict__ starts,
    const int* __restrict__ lens, const ushort* __restrict__ W1t,
    const float* __restrict__ b1, const float* __restrict__ W2,
    const float* __restrict__ b2, float* __restrict__ out) {
    __shared__ ushort Asw[RPB * DIN];        // 16KB, XOR-swizzled rows
    __shared__ float  red[4][RPB][DOUT];     // 768B

    const int raw  = blockIdx.x;             // 0..511
    const int bid  = (raw & 7) * 64 + (raw >> 3);   // XCD-chunked bijection
    const int row0 = bid * RPB;
    const int b    = row0 >> 9;              // batch (512 rows per batch)
    const int tid  = threadIdx.x;
    const int w    = tid >> 6;               // wave 0..3
    const int l    = tid & 63;
    const int m    = l & 15;
    const int g    = l >> 4;

    // ---- phase 1: segment means, interleaved across all 16 rows ----
    int s_arr[RPB], n_arr[RPB];
    int nmax = 0;
    #pragma unroll
    for (int rl = 0; rl < RPB; ++rl) {
        const int row = row0 + rl;
        const int len = lens[row];
        int s = starts[row];
        int e = min(s + len, LL);
        s = min(s, LL);
        const int n = e - s;
        s_arr[rl] = s;
        n_arr[rl] = n;
        nmax = max(nmax, n);
    }
    float a0[RPB], a1[RPB];
    #pragma unroll
    for (int rl = 0; rl < RPB; ++rl) { a0[rl] = 0.0f; a1[rl] = 0.0f; }

    const float* base = hs + (size_t)b * LL * DIN + tid * 2;
    for (int i = 0; i < nmax; ++i) {
        #pragma unroll
        for (int rl = 0; rl < RPB; ++rl) {
            if (i < n_arr[rl]) {
                const float2 v =
                    *(const float2*)(base + (size_t)(s_arr[rl] + i) * DIN);
                a0[rl] += v.x;
                a1[rl] += v.y;
            }
        }
    }
    #pragma unroll
    for (int rl = 0; rl < RPB; ++rl) {
        const float inv = (n_arr[rl] > 0) ? 1.0f / (float)n_arr[rl] : 0.0f;
        ushort2 u;
        u.x = f2bf(a0[rl] * inv);
        u.y = f2bf(a1[rl] * inv);
        *(ushort2*)((char*)Asw + rl * 1024 + ((tid * 4) ^ ((rl & 7) << 4))) = u;
    }
    __syncthreads();

    // ---- phase 2: GEMM 16 x 64 (this wave) over K = 512 ----
    f32x4 acc[4] = {{0.f, 0.f, 0.f, 0.f}, {0.f, 0.f, 0.f, 0.f},
                    {0.f, 0.f, 0.f, 0.f}, {0.f, 0.f, 0.f, 0.f}};
    const ushort* bp[4];
    #pragma unroll
    for (int fc = 0; fc < 4; ++fc)
        bp[fc] = W1t + (size_t)(w * 64 + fc * 16 + m) * DIN + g * 8;

    const char* abase = (const char*)Asw + m * 1024;
    const int   aswz  = (m & 7) << 4;
    #pragma unroll 4
    for (int kt = 0; kt < DIN; kt += 32) {
        const bf16x8 av = *(const bf16x8*)(abase + ((g * 16 + kt * 2) ^ aswz));
        #pragma unroll
        for (int fc = 0; fc < 4; ++fc) {
            const bf16x8 bv = *(const bf16x8*)(bp[fc] + kt);
            acc[fc] = __builtin_amdgcn_mfma_f32_16x16x32_bf16(av, bv, acc[fc],
                                                              0, 0, 0);
        }
    }

    // ---- phase 3: layer 2 (h = relu(acc+b1); p += h*W2), reduce, store ----
    float p[4][3] = {{0.f, 0.f, 0.f}, {0.f, 0.f, 0.f},
                     {0.f, 0.f, 0.f}, {0.f, 0.f, 0.f}};
    #pragma unroll
    for (int fc = 0; fc < 4; ++fc) {
        const int col = w * 64 + fc * 16 + m;
        const float bb = b1[col];
        const float w20 = W2[col * 3 + 0];
        const float w21 = W2[col * 3 + 1];
        const float w22 = W2[col * 3 + 2];
        #pragma unroll
        for (int r = 0; r < 4; ++r) {
            const float h = fmaxf(acc[fc][r] + bb, 0.0f);
            p[r][0] = fmaf(h, w20, p[r][0]);
            p[r][1] = fmaf(h, w21, p[r][1]);
            p[r][2] = fmaf(h, w22, p[r][2]);
        }
    }
    #pragma unroll
    for (int mask = 1; mask < 16; mask <<= 1)
        #pragma unroll
        for (int r = 0; r < 4; ++r)
            #pragma unroll
            for (int o = 0; o < 3; ++o)
                p[r][o] += __shfl_xor(p[r][o], mask, 64);

    if (m == 0) {
        #pragma unroll
        for (int r = 0; r < 4; ++r)
            #pragma unroll
            for (int o = 0; o < 3; ++o)
                red[w][g * 4 + r][o] = p[r][o];
    }
    __syncthreads();

    if (tid < RPB * DOUT) {
        const int rl = tid / 3;
        const int o  = tid % 3;
        const float v = red[0][rl][o] + red[1][rl][o] + red[2][rl][o] +
                        red[3][rl][o] + b2[o];
        out[(size_t)(row0 + rl) * DOUT + o] = fmaxf(v, 0.0f);
    }
}

extern "C" void kernel_launch(void* const* d_in, const int* in_sizes, int n_in,
                              void* d_out, int out_size, void* d_ws, size_t ws_size,
                              hipStream_t stream) {
    const float* hs  = (const float*)d_in[0];
    const int*   ds  = (const int*)d_in[1];
    const float* W1  = (const float*)d_in[2];
    const float* b1  = (const float*)d_in[3];
    const float* W2  = (const float*)d_in[4];
    const float* b2  = (const float*)d_in[5];
    const int*   lmx = (const int*)d_in[6];

    char*   wsb    = (char*)d_ws;
    int*    starts = (int*)wsb;
    int*    lens   = (int*)(wsb + 32 * 1024);
    ushort* W1t    = (ushort*)(wsb + 64 * 1024);

    prep_kernel<<<BB + 32, 512, 0, stream>>>(ds, lmx, W1, starts, lens, W1t);
    fused_kernel<<<NROW / RPB, 256, 0, stream>>>(hs, starts, lens, W1t, b1, W2,
                                                 b2, (float*)d_out);
}

// Round 8
// 36.515 us; speedup vs baseline: 1.3353x; 1.3353x over previous
//
#include <hip/hip_runtime.h>
#include <math.h>

#define BB    16
#define LL    4096
#define TMAX  512
#define DIN   512
#define DHID  256
#define DOUT  3
#define NROW  (BB * TMAX)   // 8192
#define RPB   16            // rows per fused block

typedef __attribute__((ext_vector_type(8))) short bf16x8;   // 8 bf16 = 4 VGPR
typedef __attribute__((ext_vector_type(4))) float f32x4;

static __device__ __forceinline__ ushort f2bf(float x) {
    uint u = __builtin_bit_cast(uint, x);
    u = (u + 0x7FFFu + ((u >> 16) & 1u)) >> 16;
    return (ushort)u;
}

// ---------------------------------------------------------------------------
// ws layout (bytes):
//   [0    .. 32K )  starts (int[8192])
//   [32K  .. 64K )  lens   (int[8192])
//   [64K  .. 320K)  W1t bf16 [DHID][DIN] (ushort)
// ---------------------------------------------------------------------------

// ---------------------------------------------------------------------------
// Prep: blocks 0..15 = per-batch duration scan; blocks 16..47 = W1 transpose
// to bf16 [256][512] (64x64 tiles).
// ---------------------------------------------------------------------------
__global__ __launch_bounds__(512) void prep_kernel(
    const int* __restrict__ ds, const int* __restrict__ lmax,
    const float* __restrict__ W1, int* __restrict__ starts,
    int* __restrict__ lens, ushort* __restrict__ W1t) {
    __shared__ int   sbuf[TMAX];
    __shared__ float t[64][65];
    const int bid = blockIdx.x;
    const int tid = threadIdx.x;

    if (bid < BB) {                       // ---- scan ----
        const int b = bid;
        const float mult = (float)LL / (float)lmax[0];
        const int dsv = ds[b * TMAX + tid];
        int d = (int)floorf((float)dsv * mult);
        d = max(d, 1);
        const int deff = (dsv > 0) ? d : 0;
        sbuf[tid] = deff;
        __syncthreads();
        for (int off = 1; off < TMAX; off <<= 1) {
            int x = (tid >= off) ? sbuf[tid - off] : 0;
            __syncthreads();
            sbuf[tid] += x;
            __syncthreads();
        }
        starts[b * TMAX + tid] = sbuf[tid] - deff;
        lens[b * TMAX + tid]   = deff;
    } else {                              // ---- W1 transpose ----
        const int tb = bid - BB;          // 0..31: 8 k-tiles x 4 n-tiles
        const int k0 = (tb >> 2) * 64;
        const int n0 = (tb & 3) * 64;
        const int r  = tid >> 3;          // 0..63
        const int c8 = (tid & 7) * 8;     // 0..56
        #pragma unroll
        for (int i = 0; i < 2; ++i) {
            const float4 v =
                *(const float4*)&W1[(size_t)(k0 + r) * DHID + n0 + c8 + i * 4];
            t[r][c8 + i * 4 + 0] = v.x;
            t[r][c8 + i * 4 + 1] = v.y;
            t[r][c8 + i * 4 + 2] = v.z;
            t[r][c8 + i * 4 + 3] = v.w;
        }
        __syncthreads();
        #pragma unroll
        for (int i = 0; i < 2; ++i) {
            ushort4 u;
            u.x = f2bf(t[c8 + i * 4 + 0][r]);
            u.y = f2bf(t[c8 + i * 4 + 1][r]);
            u.z = f2bf(t[c8 + i * 4 + 2][r]);
            u.w = f2bf(t[c8 + i * 4 + 3][r]);
            *(ushort4*)&W1t[(size_t)(n0 + r) * DIN + k0 + c8 + i * 4] = u;
        }
    }
}

// ---------------------------------------------------------------------------
// Fused: segment-mean (16 rows -> swizzled LDS bf16 A-tile) + MFMA GEMM
// (16x256, K=512, B = W1t direct from L2) + fused layer-2 -> d_out.
// Phase 1: frame-index OUTER; per step, 16 UNCONDITIONAL clamped loads into
//          v[16] (back-to-back issue, no branch between load and use), then
//          16 masked adds via cndmask. MLP = 16 -> BW-bound, not
//          latency-bound. Exhausted rows re-read their last frame (L1 hit).
// Phase 2: wave w owns cols w*64..w*64+63 (4 x 16x16x32 MFMA frags).
//   A-frag: lane holds A[row=l&15][k=8*(l>>4)+j] via swizzled 16B LDS read
//   B-frag: lane holds W1t[col][k] 16B global load (L2-resident)
//   C/D:    col = l&15, row = (l>>4)*4 + reg
// Grid = 512 blocks, XCD-chunked bijection (512 = 8 x 64).
// ---------------------------------------------------------------------------
__global__ __launch_bounds__(256, 2) void fused_kernel(
    const float* __restrict__ hs, const int* __restrict__ starts,
    const int* __restrict__ lens, const ushort* __restrict__ W1t,
    const float* __restrict__ b1, const float* __restrict__ W2,
    const float* __restrict__ b2, float* __restrict__ out) {
    __shared__ ushort Asw[RPB * DIN];        // 16KB, XOR-swizzled rows
    __shared__ float  red[4][RPB][DOUT];     // 768B

    const int raw  = blockIdx.x;             // 0..511
    const int bid  = (raw & 7) * 64 + (raw >> 3);   // XCD-chunked bijection
    const int row0 = bid * RPB;
    const int b    = row0 >> 9;              // batch (512 rows per batch)
    const int tid  = threadIdx.x;
    const int w    = tid >> 6;               // wave 0..3
    const int l    = tid & 63;
    const int m    = l & 15;
    const int g    = l >> 4;

    // ---- phase 1: segment means, 16-deep unconditional masked loads ----
    int s_arr[RPB], n_arr[RPB], last_arr[RPB];
    int nmax = 0;
    #pragma unroll
    for (int rl = 0; rl < RPB; ++rl) {
        const int row = row0 + rl;
        const int len = lens[row];
        int s = starts[row];
        int e = min(s + len, LL);
        s = min(s, LL);
        const int n = e - s;
        s_arr[rl]    = s;
        n_arr[rl]    = n;
        last_arr[rl] = min(max(e - 1, 0), LL - 1);   // always-valid frame
        nmax = max(nmax, n);
    }
    float a0[RPB], a1[RPB];
    #pragma unroll
    for (int rl = 0; rl < RPB; ++rl) { a0[rl] = 0.0f; a1[rl] = 0.0f; }

    const float* base = hs + (size_t)b * LL * DIN + tid * 2;
    for (int i = 0; i < nmax; ++i) {
        float2 v[RPB];
        #pragma unroll
        for (int rl = 0; rl < RPB; ++rl) {
            const int idx = min(s_arr[rl] + i, last_arr[rl]);
            v[rl] = *(const float2*)(base + (size_t)idx * DIN);
        }
        #pragma unroll
        for (int rl = 0; rl < RPB; ++rl) {
            const bool ok = (i < n_arr[rl]);
            a0[rl] += ok ? v[rl].x : 0.0f;
            a1[rl] += ok ? v[rl].y : 0.0f;
        }
    }
    #pragma unroll
    for (int rl = 0; rl < RPB; ++rl) {
        const float inv = (n_arr[rl] > 0) ? 1.0f / (float)n_arr[rl] : 0.0f;
        ushort2 u;
        u.x = f2bf(a0[rl] * inv);
        u.y = f2bf(a1[rl] * inv);
        *(ushort2*)((char*)Asw + rl * 1024 + ((tid * 4) ^ ((rl & 7) << 4))) = u;
    }
    __syncthreads();

    // ---- phase 2: GEMM 16 x 64 (this wave) over K = 512 ----
    f32x4 acc[4] = {{0.f, 0.f, 0.f, 0.f}, {0.f, 0.f, 0.f, 0.f},
                    {0.f, 0.f, 0.f, 0.f}, {0.f, 0.f, 0.f, 0.f}};
    const ushort* bp[4];
    #pragma unroll
    for (int fc = 0; fc < 4; ++fc)
        bp[fc] = W1t + (size_t)(w * 64 + fc * 16 + m) * DIN + g * 8;

    const char* abase = (const char*)Asw + m * 1024;
    const int   aswz  = (m & 7) << 4;
    #pragma unroll 4
    for (int kt = 0; kt < DIN; kt += 32) {
        const bf16x8 av = *(const bf16x8*)(abase + ((g * 16 + kt * 2) ^ aswz));
        #pragma unroll
        for (int fc = 0; fc < 4; ++fc) {
            const bf16x8 bv = *(const bf16x8*)(bp[fc] + kt);
            acc[fc] = __builtin_amdgcn_mfma_f32_16x16x32_bf16(av, bv, acc[fc],
                                                              0, 0, 0);
        }
    }

    // ---- phase 3: layer 2 (h = relu(acc+b1); p += h*W2), reduce, store ----
    float p[4][3] = {{0.f, 0.f, 0.f}, {0.f, 0.f, 0.f},
                     {0.f, 0.f, 0.f}, {0.f, 0.f, 0.f}};
    #pragma unroll
    for (int fc = 0; fc < 4; ++fc) {
        const int col = w * 64 + fc * 16 + m;
        const float bb = b1[col];
        const float w20 = W2[col * 3 + 0];
        const float w21 = W2[col * 3 + 1];
        const float w22 = W2[col * 3 + 2];
        #pragma unroll
        for (int r = 0; r < 4; ++r) {
            const float h = fmaxf(acc[fc][r] + bb, 0.0f);
            p[r][0] = fmaf(h, w20, p[r][0]);
            p[r][1] = fmaf(h, w21, p[r][1]);
            p[r][2] = fmaf(h, w22, p[r][2]);
        }
    }
    #pragma unroll
    for (int mask = 1; mask < 16; mask <<= 1)
        #pragma unroll
        for (int r = 0; r < 4; ++r)
            #pragma unroll
            for (int o = 0; o < 3; ++o)
                p[r][o] += __shfl_xor(p[r][o], mask, 64);

    if (m == 0) {
        #pragma unroll
        for (int r = 0; r < 4; ++r)
            #pragma unroll
            for (int o = 0; o < 3; ++o)
                red[w][g * 4 + r][o] = p[r][o];
    }
    __syncthreads();

    if (tid < RPB * DOUT) {
        const int rl = tid / 3;
        const int o  = tid % 3;
        const float v = red[0][rl][o] + red[1][rl][o] + red[2][rl][o] +
                        red[3][rl][o] + b2[o];
        out[(size_t)(row0 + rl) * DOUT + o] = fmaxf(v, 0.0f);
    }
}

extern "C" void kernel_launch(void* const* d_in, const int* in_sizes, int n_in,
                              void* d_out, int out_size, void* d_ws, size_t ws_size,
                              hipStream_t stream) {
    const float* hs  = (const float*)d_in[0];
    const int*   ds  = (const int*)d_in[1];
    const float* W1  = (const float*)d_in[2];
    const float* b1  = (const float*)d_in[3];
    const float* W2  = (const float*)d_in[4];
    const float* b2  = (const float*)d_in[5];
    const int*   lmx = (const int*)d_in[6];

    char*   wsb    = (char*)d_ws;
    int*    starts = (int*)wsb;
    int*    lens   = (int*)(wsb + 32 * 1024);
    ushort* W1t    = (ushort*)(wsb + 64 * 1024);

    prep_kernel<<<BB + 32, 512, 0, stream>>>(ds, lmx, W1, starts, lens, W1t);
    fused_kernel<<<NROW / RPB, 256, 0, stream>>>(hs, starts, lens, W1t, b1, W2,
                                                 b2, (float*)d_out);
}

// Round 9
// 35.773 us; speedup vs baseline: 1.3630x; 1.0207x over previous
//
#include <hip/hip_runtime.h>
#include <math.h>

#define BB    16
#define LL    4096
#define TMAX  512
#define DIN   512
#define DHID  256
#define DOUT  3
#define NROW  (BB * TMAX)   // 8192
#define RPB   16            // rows per fused block
#define RPT   8             // rows per thread in phase 1 (row-half split)

typedef __attribute__((ext_vector_type(8))) short bf16x8;   // 8 bf16 = 4 VGPR
typedef __attribute__((ext_vector_type(4))) float f32x4;

static __device__ __forceinline__ ushort f2bf(float x) {
    uint u = __builtin_bit_cast(uint, x);
    u = (u + 0x7FFFu + ((u >> 16) & 1u)) >> 16;
    return (ushort)u;
}

// ---------------------------------------------------------------------------
// ws layout (bytes):
//   [0    .. 32K )  starts (int[8192])
//   [32K  .. 64K )  lens   (int[8192])
//   [64K  .. 320K)  W1t bf16 [DHID][DIN] (ushort)
// ---------------------------------------------------------------------------

// ---------------------------------------------------------------------------
// Prep: blocks 0..15 = per-batch duration scan; blocks 16..47 = W1 transpose
// to bf16 [256][512] (64x64 tiles).
// ---------------------------------------------------------------------------
__global__ __launch_bounds__(512) void prep_kernel(
    const int* __restrict__ ds, const int* __restrict__ lmax,
    const float* __restrict__ W1, int* __restrict__ starts,
    int* __restrict__ lens, ushort* __restrict__ W1t) {
    __shared__ int   sbuf[TMAX];
    __shared__ float t[64][65];
    const int bid = blockIdx.x;
    const int tid = threadIdx.x;

    if (bid < BB) {                       // ---- scan ----
        const int b = bid;
        const float mult = (float)LL / (float)lmax[0];
        const int dsv = ds[b * TMAX + tid];
        int d = (int)floorf((float)dsv * mult);
        d = max(d, 1);
        const int deff = (dsv > 0) ? d : 0;
        sbuf[tid] = deff;
        __syncthreads();
        for (int off = 1; off < TMAX; off <<= 1) {
            int x = (tid >= off) ? sbuf[tid - off] : 0;
            __syncthreads();
            sbuf[tid] += x;
            __syncthreads();
        }
        starts[b * TMAX + tid] = sbuf[tid] - deff;
        lens[b * TMAX + tid]   = deff;
    } else {                              // ---- W1 transpose ----
        const int tb = bid - BB;          // 0..31: 8 k-tiles x 4 n-tiles
        const int k0 = (tb >> 2) * 64;
        const int n0 = (tb & 3) * 64;
        const int r  = tid >> 3;          // 0..63
        const int c8 = (tid & 7) * 8;     // 0..56
        #pragma unroll
        for (int i = 0; i < 2; ++i) {
            const float4 v =
                *(const float4*)&W1[(size_t)(k0 + r) * DHID + n0 + c8 + i * 4];
            t[r][c8 + i * 4 + 0] = v.x;
            t[r][c8 + i * 4 + 1] = v.y;
            t[r][c8 + i * 4 + 2] = v.z;
            t[r][c8 + i * 4 + 3] = v.w;
        }
        __syncthreads();
        #pragma unroll
        for (int i = 0; i < 2; ++i) {
            ushort4 u;
            u.x = f2bf(t[c8 + i * 4 + 0][r]);
            u.y = f2bf(t[c8 + i * 4 + 1][r]);
            u.z = f2bf(t[c8 + i * 4 + 2][r]);
            u.w = f2bf(t[c8 + i * 4 + 3][r]);
            *(ushort4*)&W1t[(size_t)(n0 + r) * DIN + k0 + c8 + i * 4] = u;
        }
    }
}

// ---------------------------------------------------------------------------
// Fused: segment-mean (16 rows -> swizzled LDS bf16 A-tile) + MFMA GEMM
// (16x256, K=512, B = W1t direct from L2) + fused layer-2 -> d_out.
// 512 threads / 8 waves per block; 512 blocks -> 16 waves/CU (4/SIMD).
// Phase 1: thread = (col-pair ct = tid&255, row-half rh = tid>>8);
//          8 rows x nmax clamped UNCONDITIONAL loads, masked cndmask adds
//          (16-deep MLP per wave, same total loads as R8, 2x the waves).
// Phase 2: wave w (0..7) owns cols w*32..w*32+31 (2 x 16x16x32 MFMA frags)
//          -- per-block phase-2 work identical to the 4-wave version.
//   A-frag: lane holds A[row=l&15][k=8*(l>>4)+j] via swizzled 16B LDS read
//   B-frag: lane holds W1t[col][k] 16B global load (L2-resident)
//   C/D:    col = l&15, row = (l>>4)*4 + reg
// Grid = 512 blocks, XCD-chunked bijection (512 = 8 x 64).
// ---------------------------------------------------------------------------
__global__ __launch_bounds__(512, 4) void fused_kernel(
    const float* __restrict__ hs, const int* __restrict__ starts,
    const int* __restrict__ lens, const ushort* __restrict__ W1t,
    const float* __restrict__ b1, const float* __restrict__ W2,
    const float* __restrict__ b2, float* __restrict__ out) {
    __shared__ ushort Asw[RPB * DIN];        // 16KB, XOR-swizzled rows
    __shared__ float  red[8][RPB][DOUT];     // 1.5KB

    const int raw  = blockIdx.x;             // 0..511
    const int bid  = (raw & 7) * 64 + (raw >> 3);   // XCD-chunked bijection
    const int row0 = bid * RPB;
    const int b    = row0 >> 9;              // batch (512 rows per batch)
    const int tid  = threadIdx.x;
    const int w    = tid >> 6;               // wave 0..7
    const int l    = tid & 63;
    const int m    = l & 15;
    const int g    = l >> 4;
    const int ct   = tid & 255;              // col-pair owner (phase 1)
    const int rh   = tid >> 8;               // row-half (phase 1)

    // ---- phase 1: segment means, 8 rows/thread, unconditional loads ----
    int s_arr[RPT], n_arr[RPT], last_arr[RPT];
    int nmax = 0;
    #pragma unroll
    for (int rr = 0; rr < RPT; ++rr) {
        const int row = row0 + rh * RPT + rr;
        const int len = lens[row];
        int s = starts[row];
        int e = min(s + len, LL);
        s = min(s, LL);
        const int n = e - s;
        s_arr[rr]    = s;
        n_arr[rr]    = n;
        last_arr[rr] = min(max(e - 1, 0), LL - 1);   // always-valid frame
        nmax = max(nmax, n);
    }
    float a0[RPT], a1[RPT];
    #pragma unroll
    for (int rr = 0; rr < RPT; ++rr) { a0[rr] = 0.0f; a1[rr] = 0.0f; }

    const float* base = hs + (size_t)b * LL * DIN + ct * 2;
    for (int i = 0; i < nmax; ++i) {
        float2 v[RPT];
        #pragma unroll
        for (int rr = 0; rr < RPT; ++rr) {
            const int idx = min(s_arr[rr] + i, last_arr[rr]);
            v[rr] = *(const float2*)(base + (size_t)idx * DIN);
        }
        #pragma unroll
        for (int rr = 0; rr < RPT; ++rr) {
            const bool ok = (i < n_arr[rr]);
            a0[rr] += ok ? v[rr].x : 0.0f;
            a1[rr] += ok ? v[rr].y : 0.0f;
        }
    }
    #pragma unroll
    for (int rr = 0; rr < RPT; ++rr) {
        const int rl = rh * RPT + rr;
        const float inv = (n_arr[rr] > 0) ? 1.0f / (float)n_arr[rr] : 0.0f;
        ushort2 u;
        u.x = f2bf(a0[rr] * inv);
        u.y = f2bf(a1[rr] * inv);
        *(ushort2*)((char*)Asw + rl * 1024 + ((ct * 4) ^ ((rl & 7) << 4))) = u;
    }
    __syncthreads();

    // ---- phase 2: GEMM 16 x 32 (this wave) over K = 512 ----
    f32x4 acc[2] = {{0.f, 0.f, 0.f, 0.f}, {0.f, 0.f, 0.f, 0.f}};
    const ushort* bp[2];
    #pragma unroll
    for (int fc = 0; fc < 2; ++fc)
        bp[fc] = W1t + (size_t)(w * 32 + fc * 16 + m) * DIN + g * 8;

    const char* abase = (const char*)Asw + m * 1024;
    const int   aswz  = (m & 7) << 4;
    #pragma unroll 4
    for (int kt = 0; kt < DIN; kt += 32) {
        const bf16x8 av = *(const bf16x8*)(abase + ((g * 16 + kt * 2) ^ aswz));
        #pragma unroll
        for (int fc = 0; fc < 2; ++fc) {
            const bf16x8 bv = *(const bf16x8*)(bp[fc] + kt);
            acc[fc] = __builtin_amdgcn_mfma_f32_16x16x32_bf16(av, bv, acc[fc],
                                                              0, 0, 0);
        }
    }

    // ---- phase 3: layer 2 (h = relu(acc+b1); p += h*W2), reduce, store ----
    float p[4][3] = {{0.f, 0.f, 0.f}, {0.f, 0.f, 0.f},
                     {0.f, 0.f, 0.f}, {0.f, 0.f, 0.f}};
    #pragma unroll
    for (int fc = 0; fc < 2; ++fc) {
        const int col = w * 32 + fc * 16 + m;
        const float bb = b1[col];
        const float w20 = W2[col * 3 + 0];
        const float w21 = W2[col * 3 + 1];
        const float w22 = W2[col * 3 + 2];
        #pragma unroll
        for (int r = 0; r < 4; ++r) {
            const float h = fmaxf(acc[fc][r] + bb, 0.0f);
            p[r][0] = fmaf(h, w20, p[r][0]);
            p[r][1] = fmaf(h, w21, p[r][1]);
            p[r][2] = fmaf(h, w22, p[r][2]);
        }
    }
    #pragma unroll
    for (int mask = 1; mask < 16; mask <<= 1)
        #pragma unroll
        for (int r = 0; r < 4; ++r)
            #pragma unroll
            for (int o = 0; o < 3; ++o)
                p[r][o] += __shfl_xor(p[r][o], mask, 64);

    if (m == 0) {
        #pragma unroll
        for (int r = 0; r < 4; ++r)
            #pragma unroll
            for (int o = 0; o < 3; ++o)
                red[w][g * 4 + r][o] = p[r][o];
    }
    __syncthreads();

    if (tid < RPB * DOUT) {
        const int rl = tid / 3;
        const int o  = tid % 3;
        float v = b2[o];
        #pragma unroll
        for (int ww = 0; ww < 8; ++ww) v += red[ww][rl][o];
        out[(size_t)(row0 + rl) * DOUT + o] = fmaxf(v, 0.0f);
    }
}

extern "C" void kernel_launch(void* const* d_in, const int* in_sizes, int n_in,
                              void* d_out, int out_size, void* d_ws, size_t ws_size,
                              hipStream_t stream) {
    const float* hs  = (const float*)d_in[0];
    const int*   ds  = (const int*)d_in[1];
    const float* W1  = (const float*)d_in[2];
    const float* b1  = (const float*)d_in[3];
    const float* W2  = (const float*)d_in[4];
    const float* b2  = (const float*)d_in[5];
    const int*   lmx = (const int*)d_in[6];

    char*   wsb    = (char*)d_ws;
    int*    starts = (int*)wsb;
    int*    lens   = (int*)(wsb + 32 * 1024);
    ushort* W1t    = (ushort*)(wsb + 64 * 1024);

    prep_kernel<<<BB + 32, 512, 0, stream>>>(ds, lmx, W1, starts, lens, W1t);
    fused_kernel<<<NROW / RPB, 512, 0, stream>>>(hs, starts, lens, W1t, b1, W2,
                                                 b2, (float*)d_out);
}